// Round 3
// baseline (367.989 us; speedup 1.0000x reference)
//
#include <hip/hip_runtime.h>

#define N_NODES 50000
#define N_EDGES 800000
#define IN_DIM 128
#define OUT_DIM 64
#define NEG_SLOPE 0.01f

// K0: zero histogram; compute c = W_feat . Wa_feat
__global__ void k_init(int* __restrict__ cnt, float* __restrict__ c_ws,
                       const float* __restrict__ W_attn,
                       const float* __restrict__ W_feat) {
    int i = blockIdx.x * blockDim.x + threadIdx.x;
    int stride = gridDim.x * blockDim.x;
    for (int j = i; j < N_NODES; j += stride) cnt[j] = 0;
    if (blockIdx.x == 0 && threadIdx.x < 64) {
        int lane = threadIdx.x;
        float p = W_feat[lane] * W_attn[128 + lane];
        #pragma unroll
        for (int off = 32; off; off >>= 1) p += __shfl_xor(p, off, 64);
        if (lane == 0) c_ws[0] = p;
    }
}

// K1: z = h @ W_fc (f32), a_src = z . Wa_src, a_dst = z . Wa_dst
__launch_bounds__(256)
__global__ void k_fc(const float* __restrict__ h,
                     const float* __restrict__ W_fc,
                     const float* __restrict__ W_attn,
                     float* __restrict__ z, float* __restrict__ a_src, float* __restrict__ a_dst) {
    __shared__ float Wlds[IN_DIM * OUT_DIM];  // 32 KB
    const float4* Wg = (const float4*)W_fc;
    float4* Wl = (float4*)Wlds;
    for (int i = threadIdx.x; i < IN_DIM * OUT_DIM / 4; i += 256) Wl[i] = Wg[i];
    __syncthreads();

    const int lane = threadIdx.x & 63;
    const int wid  = threadIdx.x >> 6;
    const float was = W_attn[lane];
    const float wad = W_attn[64 + lane];
    const int wavesTotal = gridDim.x * 4;

    for (int n = blockIdx.x * 4 + wid; n < N_NODES; n += wavesTotal) {
        float2 hp = ((const float2*)h)[n * (IN_DIM / 2) + lane];
        float zd = 0.f;
        #pragma unroll
        for (int kk = 0; kk < 64; ++kk) {
            float h0 = __shfl(hp.x, kk, 64);
            float h1 = __shfl(hp.y, kk, 64);
            zd += h0 * Wlds[(2 * kk) * OUT_DIM + lane];
            zd += h1 * Wlds[(2 * kk + 1) * OUT_DIM + lane];
        }
        z[n * OUT_DIM + lane] = zd;
        float ps = zd * was, pd = zd * wad;
        #pragma unroll
        for (int off = 32; off; off >>= 1) {
            ps += __shfl_xor(ps, off, 64);
            pd += __shfl_xor(pd, off, 64);
        }
        if (lane == 0) { a_src[n] = ps; a_dst[n] = pd; }
    }
}

// K2: histogram of dst
__global__ void k_hist(const int* __restrict__ dst, int* __restrict__ cnt) {
    int i = blockIdx.x * blockDim.x + threadIdx.x;
    int stride = gridDim.x * blockDim.x;
    for (int e = i; e < N_EDGES; e += stride) atomicAdd(&cnt[dst[e]], 1);
}

// K3: single-block exclusive scan of cnt -> start, cursor
__launch_bounds__(1024)
__global__ void k_scan(const int* __restrict__ cnt, int* __restrict__ start, int* __restrict__ cursor) {
    __shared__ int part[1024];
    const int t = threadIdx.x;
    const int per = (N_NODES + 1023) / 1024;
    int lo = t * per, hi = lo + per; if (hi > N_NODES) hi = N_NODES;
    int s = 0;
    for (int i = lo; i < hi; i++) s += cnt[i];
    part[t] = s;
    __syncthreads();
    for (int off = 1; off < 1024; off <<= 1) {
        int u = (t >= off) ? part[t - off] : 0;
        __syncthreads();
        part[t] += u;
        __syncthreads();
    }
    int run = part[t] - s;  // exclusive prefix of this thread's chunk
    for (int i = lo; i < hi; i++) { start[i] = run; cursor[i] = run; run += cnt[i]; }
}

// K4: compute ex per edge, scatter (src, ex) into dst-sorted buckets
__launch_bounds__(256)
__global__ void k_scatter(const int* __restrict__ src, const int* __restrict__ dst,
                          const float* __restrict__ embed,
                          const float* __restrict__ a_src, const float* __restrict__ a_dst,
                          const float* __restrict__ c_ws,
                          int* __restrict__ cursor,
                          int* __restrict__ sorted_src, float* __restrict__ sorted_ex) {
    int e = blockIdx.x * 256 + threadIdx.x;
    if (e >= N_EDGES) return;
    int s = src[e], d = dst[e];
    float ev = a_src[s] + a_dst[d] + c_ws[0] * embed[e];
    ev = (ev >= 0.f) ? ev : NEG_SLOPE * ev;
    float ex = __expf(ev);  // segment-max skipped: softmax shift-invariant, e is O(5)
    int pos = atomicAdd(&cursor[d], 1);
    sorted_src[pos] = s;
    sorted_ex[pos] = ex;
}

// K5: one wave per node: out[n] = sum(ex * z[s]) / sum(ex)
__launch_bounds__(256)
__global__ void k_gather(const int* __restrict__ start, const int* __restrict__ cnt,
                         const int* __restrict__ sorted_src, const float* __restrict__ sorted_ex,
                         const float* __restrict__ z, float* __restrict__ out) {
    int n = blockIdx.x * 4 + (threadIdx.x >> 6);
    if (n >= N_NODES) return;
    int lane = threadIdx.x & 63;
    int b = start[n], c = cnt[n];
    float acc = 0.f, den = 0.f;
    for (int j = b; j < b + c; j++) {
        int s = sorted_src[j];
        float ex = sorted_ex[j];
        den += ex;
        acc += ex * z[s * OUT_DIM + lane];
    }
    out[n * OUT_DIM + lane] = c ? acc / den : 0.f;
}

extern "C" void kernel_launch(void* const* d_in, const int* in_sizes, int n_in,
                              void* d_out, int out_size, void* d_ws, size_t ws_size,
                              hipStream_t stream) {
    const float* h      = (const float*)d_in[0];
    const float* embed  = (const float*)d_in[1];
    const int*   src    = (const int*)d_in[2];
    const int*   dst    = (const int*)d_in[3];
    const float* W_fc   = (const float*)d_in[4];
    const float* W_attn = (const float*)d_in[5];
    const float* W_feat = (const float*)d_in[6];

    float* ws         = (float*)d_ws;
    float* z          = ws;                          // N*64 f32
    float* sorted_ex  = z + N_NODES * OUT_DIM;       // E f32
    float* a_src      = sorted_ex + N_EDGES;         // N f32
    float* a_dst      = a_src + N_NODES;             // N f32
    float* c_ws       = a_dst + N_NODES;             // 1 f32
    int*   sorted_src = (int*)(c_ws + 1);            // E int
    int*   cnt        = sorted_src + N_EDGES;        // N int
    int*   start      = cnt + N_NODES;               // N int
    int*   cursor     = start + N_NODES;             // N int

    float* out = (float*)d_out;

    k_init<<<512, 256, 0, stream>>>(cnt, c_ws, W_attn, W_feat);
    k_fc<<<1024, 256, 0, stream>>>(h, W_fc, W_attn, z, a_src, a_dst);
    k_hist<<<1024, 256, 0, stream>>>(dst, cnt);
    k_scan<<<1, 1024, 0, stream>>>(cnt, start, cursor);
    k_scatter<<<(N_EDGES + 255) / 256, 256, 0, stream>>>(src, dst, embed, a_src, a_dst, c_ws,
                                                         cursor, sorted_src, sorted_ex);
    k_gather<<<(N_NODES + 3) / 4, 256, 0, stream>>>(start, cnt, sorted_src, sorted_ex, z, out);
}

// Round 4
// 257.235 us; speedup vs baseline: 1.4306x; 1.4306x over previous
//
#include <hip/hip_runtime.h>

#define N_NODES 50000
#define N_EDGES 800000
#define IN_DIM 128
#define OUT_DIM 64
#define NEG_SLOPE 0.01f

#define SCAN_CHUNK 256
#define NB_SCAN ((N_NODES + SCAN_CHUNK - 1) / SCAN_CHUNK)  // 196

// K0: zero histogram; compute c = W_feat . Wa_feat
__global__ void k_init(int* __restrict__ cnt, float* __restrict__ c_ws,
                       const float* __restrict__ W_attn,
                       const float* __restrict__ W_feat) {
    int i = blockIdx.x * blockDim.x + threadIdx.x;
    int stride = gridDim.x * blockDim.x;
    for (int j = i; j < N_NODES; j += stride) cnt[j] = 0;
    if (blockIdx.x == 0 && threadIdx.x < 64) {
        int lane = threadIdx.x;
        float p = W_feat[lane] * W_attn[128 + lane];
        #pragma unroll
        for (int off = 32; off; off >>= 1) p += __shfl_xor(p, off, 64);
        if (lane == 0) c_ws[0] = p;
    }
}

// K1: z = h @ W_fc (f32), a_src = z . Wa_src, a_dst = z . Wa_dst
__launch_bounds__(256)
__global__ void k_fc(const float* __restrict__ h,
                     const float* __restrict__ W_fc,
                     const float* __restrict__ W_attn,
                     float* __restrict__ z, float* __restrict__ a_src, float* __restrict__ a_dst) {
    __shared__ float Wlds[IN_DIM * OUT_DIM];  // 32 KB
    const float4* Wg = (const float4*)W_fc;
    float4* Wl = (float4*)Wlds;
    for (int i = threadIdx.x; i < IN_DIM * OUT_DIM / 4; i += 256) Wl[i] = Wg[i];
    __syncthreads();

    const int lane = threadIdx.x & 63;
    const int wid  = threadIdx.x >> 6;
    const float was = W_attn[lane];
    const float wad = W_attn[64 + lane];
    const int wavesTotal = gridDim.x * 4;

    for (int n = blockIdx.x * 4 + wid; n < N_NODES; n += wavesTotal) {
        float2 hp = ((const float2*)h)[n * (IN_DIM / 2) + lane];
        float zd = 0.f;
        #pragma unroll
        for (int kk = 0; kk < 64; ++kk) {
            float h0 = __shfl(hp.x, kk, 64);
            float h1 = __shfl(hp.y, kk, 64);
            zd += h0 * Wlds[(2 * kk) * OUT_DIM + lane];
            zd += h1 * Wlds[(2 * kk + 1) * OUT_DIM + lane];
        }
        z[n * OUT_DIM + lane] = zd;
        float ps = zd * was, pd = zd * wad;
        #pragma unroll
        for (int off = 32; off; off >>= 1) {
            ps += __shfl_xor(ps, off, 64);
            pd += __shfl_xor(pd, off, 64);
        }
        if (lane == 0) { a_src[n] = ps; a_dst[n] = pd; }
    }
}

// K2: histogram of dst
__global__ void k_hist(const int* __restrict__ dst, int* __restrict__ cnt) {
    int i = blockIdx.x * blockDim.x + threadIdx.x;
    int stride = gridDim.x * blockDim.x;
    for (int e = i; e < N_EDGES; e += stride) atomicAdd(&cnt[dst[e]], 1);
}

// K3a: per-block chunk sums
__launch_bounds__(256)
__global__ void k_scan_a(const int* __restrict__ cnt, int* __restrict__ blocksum) {
    __shared__ int red[4];
    int t = threadIdx.x, i = blockIdx.x * SCAN_CHUNK + t;
    int v = (i < N_NODES) ? cnt[i] : 0;
    int s = v;
    #pragma unroll
    for (int off = 32; off; off >>= 1) s += __shfl_xor(s, off, 64);
    if ((t & 63) == 0) red[t >> 6] = s;
    __syncthreads();
    if (t == 0) blocksum[blockIdx.x] = red[0] + red[1] + red[2] + red[3];
}

// K3b: single small block scans blocksum -> exclusive block offsets
__launch_bounds__(256)
__global__ void k_scan_b(const int* __restrict__ blocksum, int* __restrict__ bloff) {
    __shared__ int part[256];
    int t = threadIdx.x;
    int v = (t < NB_SCAN) ? blocksum[t] : 0;
    part[t] = v;
    __syncthreads();
    #pragma unroll
    for (int off = 1; off < 256; off <<= 1) {
        int u = (t >= off) ? part[t - off] : 0;
        __syncthreads();
        part[t] += u;
        __syncthreads();
    }
    if (t < NB_SCAN) bloff[t] = part[t] - v;  // exclusive
}

// K3c: per-block exclusive scan + block offset -> start, cursor
__launch_bounds__(256)
__global__ void k_scan_c(const int* __restrict__ cnt, const int* __restrict__ bloff,
                         int* __restrict__ start, int* __restrict__ cursor) {
    __shared__ int part[256];
    int t = threadIdx.x, i = blockIdx.x * SCAN_CHUNK + t;
    int v = (i < N_NODES) ? cnt[i] : 0;
    part[t] = v;
    __syncthreads();
    #pragma unroll
    for (int off = 1; off < 256; off <<= 1) {
        int u = (t >= off) ? part[t - off] : 0;
        __syncthreads();
        part[t] += u;
        __syncthreads();
    }
    if (i < N_NODES) {
        int r = bloff[blockIdx.x] + part[t] - v;
        start[i] = r;
        cursor[i] = r;
    }
}

// K4: compute ex per edge, scatter packed (src, ex) into dst-sorted buckets
__launch_bounds__(256)
__global__ void k_scatter(const int* __restrict__ src, const int* __restrict__ dst,
                          const float* __restrict__ embed,
                          const float* __restrict__ a_src, const float* __restrict__ a_dst,
                          const float* __restrict__ c_ws,
                          int* __restrict__ cursor,
                          int2* __restrict__ sorted_pair) {
    int e = blockIdx.x * 256 + threadIdx.x;
    if (e >= N_EDGES) return;
    int s = src[e], d = dst[e];
    float ev = a_src[s] + a_dst[d] + c_ws[0] * embed[e];
    ev = (ev >= 0.f) ? ev : NEG_SLOPE * ev;
    float ex = __expf(ev);  // segment-max skipped: softmax shift-invariant, e is O(5)
    int pos = atomicAdd(&cursor[d], 1);
    sorted_pair[pos] = make_int2(s, __float_as_int(ex));
}

// K5: one wave per node: out[n] = sum(ex * z[s]) / sum(ex)
__launch_bounds__(256)
__global__ void k_gather(const int* __restrict__ start, const int* __restrict__ cnt,
                         const int2* __restrict__ sorted_pair,
                         const float* __restrict__ z, float* __restrict__ out) {
    int n = blockIdx.x * 4 + (threadIdx.x >> 6);
    if (n >= N_NODES) return;
    int lane = threadIdx.x & 63;
    int b = start[n], c = cnt[n];
    float acc = 0.f, den = 0.f;
    for (int j = b; j < b + c; j++) {
        int2 p = sorted_pair[j];
        float ex = __int_as_float(p.y);
        den += ex;
        acc += ex * z[p.x * OUT_DIM + lane];
    }
    out[n * OUT_DIM + lane] = c ? acc / den : 0.f;
}

extern "C" void kernel_launch(void* const* d_in, const int* in_sizes, int n_in,
                              void* d_out, int out_size, void* d_ws, size_t ws_size,
                              hipStream_t stream) {
    const float* h      = (const float*)d_in[0];
    const float* embed  = (const float*)d_in[1];
    const int*   src    = (const int*)d_in[2];
    const int*   dst    = (const int*)d_in[3];
    const float* W_fc   = (const float*)d_in[4];
    const float* W_attn = (const float*)d_in[5];
    const float* W_feat = (const float*)d_in[6];

    float* ws          = (float*)d_ws;
    float* z           = ws;                          // N*64 f32
    float* a_src       = z + N_NODES * OUT_DIM;       // N f32
    float* a_dst       = a_src + N_NODES;             // N f32
    float* c_ws        = a_dst + N_NODES;             // 1 f32
    int2*  sorted_pair = (int2*)(c_ws + 1);           // E int2 (8B-aligned: offset is even)
    int*   cnt         = (int*)(sorted_pair + N_EDGES); // N int
    int*   start       = cnt + N_NODES;               // N int
    int*   cursor      = start + N_NODES;             // N int
    int*   blocksum    = cursor + N_NODES;            // NB_SCAN int
    int*   bloff       = blocksum + NB_SCAN;          // NB_SCAN int

    float* out = (float*)d_out;

    k_init<<<512, 256, 0, stream>>>(cnt, c_ws, W_attn, W_feat);
    k_fc<<<1024, 256, 0, stream>>>(h, W_fc, W_attn, z, a_src, a_dst);
    k_hist<<<1024, 256, 0, stream>>>(dst, cnt);
    k_scan_a<<<NB_SCAN, 256, 0, stream>>>(cnt, blocksum);
    k_scan_b<<<1, 256, 0, stream>>>(blocksum, bloff);
    k_scan_c<<<NB_SCAN, 256, 0, stream>>>(cnt, bloff, start, cursor);
    k_scatter<<<(N_EDGES + 255) / 256, 256, 0, stream>>>(src, dst, embed, a_src, a_dst, c_ws,
                                                         cursor, sorted_pair);
    k_gather<<<(N_NODES + 3) / 4, 256, 0, stream>>>(start, cnt, sorted_pair, z, out);
}

// Round 5
// 194.323 us; speedup vs baseline: 1.8937x; 1.3237x over previous
//
#include <hip/hip_runtime.h>

#define N_NODES 50000
#define N_EDGES 800000
#define IN_DIM 128
#define OUT_DIM 64
#define NEG_SLOPE 0.01f

#define SCAN_CHUNK 256
#define NB_SCAN ((N_NODES + SCAN_CHUNK - 1) / SCAN_CHUNK)  // 196

// K0: zero histogram; compute c = W_feat . Wa_feat
__global__ void k_init(int* __restrict__ cnt, float* __restrict__ c_ws,
                       const float* __restrict__ W_attn,
                       const float* __restrict__ W_feat) {
    int i = blockIdx.x * blockDim.x + threadIdx.x;
    int stride = gridDim.x * blockDim.x;
    for (int j = i; j < N_NODES; j += stride) cnt[j] = 0;
    if (blockIdx.x == 0 && threadIdx.x < 64) {
        int lane = threadIdx.x;
        float p = W_feat[lane] * W_attn[128 + lane];
        #pragma unroll
        for (int off = 32; off; off >>= 1) p += __shfl_xor(p, off, 64);
        if (lane == 0) c_ws[0] = p;
    }
}

// K1: z = h @ W_fc, a_src = z . Wa_src, a_dst = z . Wa_dst
// Thread-per-(node, output-quarter): 16 f32 accumulators in registers.
// Lanes 0-3 share a node (h loads L1-broadcast); a_* reduced over 4 lanes.
__launch_bounds__(256)
__global__ void k_fc(const float* __restrict__ h,
                     const float* __restrict__ W_fc,
                     const float* __restrict__ W_attn,
                     float* __restrict__ z, float* __restrict__ a_src, float* __restrict__ a_dst) {
    __shared__ float Wlds[IN_DIM * OUT_DIM];  // 32 KB
    const float4* Wg = (const float4*)W_fc;
    float4* Wl = (float4*)Wlds;
    #pragma unroll
    for (int i = 0; i < 8; ++i) Wl[threadIdx.x + i * 256] = Wg[threadIdx.x + i * 256];
    __syncthreads();

    int g = blockIdx.x * 256 + threadIdx.x;
    int n = g >> 2;   // node
    int q = g & 3;    // output quarter: dims [q*16, q*16+16)
    if (n >= N_NODES) return;

    float acc[16];
    #pragma unroll
    for (int i = 0; i < 16; ++i) acc[i] = 0.f;

    const float4* hrow = (const float4*)(h + (size_t)n * IN_DIM);

    for (int kc = 0; kc < IN_DIM / 4; ++kc) {   // 32 iters
        float4 hv = hrow[kc];
        #pragma unroll
        for (int j = 0; j < 4; ++j) {
            float hk = (j == 0) ? hv.x : (j == 1) ? hv.y : (j == 2) ? hv.z : hv.w;
            const float4* Wr = (const float4*)Wlds + (kc * 4 + j) * (OUT_DIM / 4) + q * 4;
            #pragma unroll
            for (int i = 0; i < 4; ++i) {
                float4 wv = Wr[i];
                acc[i * 4 + 0] += hk * wv.x;
                acc[i * 4 + 1] += hk * wv.y;
                acc[i * 4 + 2] += hk * wv.z;
                acc[i * 4 + 3] += hk * wv.w;
            }
        }
    }

    float4* zrow = (float4*)(z + (size_t)n * OUT_DIM) + q * 4;
    #pragma unroll
    for (int i = 0; i < 4; ++i)
        zrow[i] = make_float4(acc[i * 4], acc[i * 4 + 1], acc[i * 4 + 2], acc[i * 4 + 3]);

    const float* wa_s = W_attn + q * 16;
    const float* wa_d = W_attn + OUT_DIM + q * 16;
    float ps = 0.f, pd = 0.f;
    #pragma unroll
    for (int i = 0; i < 16; ++i) { ps += acc[i] * wa_s[i]; pd += acc[i] * wa_d[i]; }
    ps += __shfl_xor(ps, 1, 64); ps += __shfl_xor(ps, 2, 64);
    pd += __shfl_xor(pd, 1, 64); pd += __shfl_xor(pd, 2, 64);
    if (q == 0) { a_src[n] = ps; a_dst[n] = pd; }
}

// K2: histogram of dst
__global__ void k_hist(const int* __restrict__ dst, int* __restrict__ cnt) {
    int i = blockIdx.x * blockDim.x + threadIdx.x;
    int stride = gridDim.x * blockDim.x;
    for (int e = i; e < N_EDGES; e += stride) atomicAdd(&cnt[dst[e]], 1);
}

// K3a: per-block chunk sums
__launch_bounds__(256)
__global__ void k_scan_a(const int* __restrict__ cnt, int* __restrict__ blocksum) {
    __shared__ int red[4];
    int t = threadIdx.x, i = blockIdx.x * SCAN_CHUNK + t;
    int v = (i < N_NODES) ? cnt[i] : 0;
    int s = v;
    #pragma unroll
    for (int off = 32; off; off >>= 1) s += __shfl_xor(s, off, 64);
    if ((t & 63) == 0) red[t >> 6] = s;
    __syncthreads();
    if (t == 0) blocksum[blockIdx.x] = red[0] + red[1] + red[2] + red[3];
}

// K3b: single small block scans blocksum -> exclusive block offsets
__launch_bounds__(256)
__global__ void k_scan_b(const int* __restrict__ blocksum, int* __restrict__ bloff) {
    __shared__ int part[256];
    int t = threadIdx.x;
    int v = (t < NB_SCAN) ? blocksum[t] : 0;
    part[t] = v;
    __syncthreads();
    #pragma unroll
    for (int off = 1; off < 256; off <<= 1) {
        int u = (t >= off) ? part[t - off] : 0;
        __syncthreads();
        part[t] += u;
        __syncthreads();
    }
    if (t < NB_SCAN) bloff[t] = part[t] - v;  // exclusive
}

// K3c: per-block exclusive scan + block offset -> start, cursor
__launch_bounds__(256)
__global__ void k_scan_c(const int* __restrict__ cnt, const int* __restrict__ bloff,
                         int* __restrict__ start, int* __restrict__ cursor) {
    __shared__ int part[256];
    int t = threadIdx.x, i = blockIdx.x * SCAN_CHUNK + t;
    int v = (i < N_NODES) ? cnt[i] : 0;
    part[t] = v;
    __syncthreads();
    #pragma unroll
    for (int off = 1; off < 256; off <<= 1) {
        int u = (t >= off) ? part[t - off] : 0;
        __syncthreads();
        part[t] += u;
        __syncthreads();
    }
    if (i < N_NODES) {
        int r = bloff[blockIdx.x] + part[t] - v;
        start[i] = r;
        cursor[i] = r;
    }
}

// K4: compute ex per edge, scatter packed (src, ex) into dst-sorted buckets
__launch_bounds__(256)
__global__ void k_scatter(const int* __restrict__ src, const int* __restrict__ dst,
                          const float* __restrict__ embed,
                          const float* __restrict__ a_src, const float* __restrict__ a_dst,
                          const float* __restrict__ c_ws,
                          int* __restrict__ cursor,
                          int2* __restrict__ sorted_pair) {
    int e = blockIdx.x * 256 + threadIdx.x;
    if (e >= N_EDGES) return;
    int s = src[e], d = dst[e];
    float ev = a_src[s] + a_dst[d] + c_ws[0] * embed[e];
    ev = (ev >= 0.f) ? ev : NEG_SLOPE * ev;
    float ex = __expf(ev);  // segment-max skipped: softmax shift-invariant, e is O(5)
    int pos = atomicAdd(&cursor[d], 1);
    sorted_pair[pos] = make_int2(s, __float_as_int(ex));
}

// K5: one wave per node: out[n] = sum(ex * z[s]) / sum(ex)
__launch_bounds__(256)
__global__ void k_gather(const int* __restrict__ start, const int* __restrict__ cnt,
                         const int2* __restrict__ sorted_pair,
                         const float* __restrict__ z, float* __restrict__ out) {
    int n = blockIdx.x * 4 + (threadIdx.x >> 6);
    if (n >= N_NODES) return;
    int lane = threadIdx.x & 63;
    int b = start[n], c = cnt[n];
    float acc = 0.f, den = 0.f;
    for (int j = b; j < b + c; j++) {
        int2 p = sorted_pair[j];
        float ex = __int_as_float(p.y);
        den += ex;
        acc += ex * z[p.x * OUT_DIM + lane];
    }
    out[n * OUT_DIM + lane] = c ? acc / den : 0.f;
}

extern "C" void kernel_launch(void* const* d_in, const int* in_sizes, int n_in,
                              void* d_out, int out_size, void* d_ws, size_t ws_size,
                              hipStream_t stream) {
    const float* h      = (const float*)d_in[0];
    const float* embed  = (const float*)d_in[1];
    const int*   src    = (const int*)d_in[2];
    const int*   dst    = (const int*)d_in[3];
    const float* W_fc   = (const float*)d_in[4];
    const float* W_attn = (const float*)d_in[5];
    const float* W_feat = (const float*)d_in[6];

    float* ws          = (float*)d_ws;
    float* z           = ws;                          // N*64 f32
    float* a_src       = z + N_NODES * OUT_DIM;       // N f32
    float* a_dst       = a_src + N_NODES;             // N f32
    float* c_ws        = a_dst + N_NODES;             // 1 f32
    int2*  sorted_pair = (int2*)(c_ws + 1);           // E int2 (8B-aligned: offset is even)
    int*   cnt         = (int*)(sorted_pair + N_EDGES); // N int
    int*   start       = cnt + N_NODES;               // N int
    int*   cursor      = start + N_NODES;             // N int
    int*   blocksum    = cursor + N_NODES;            // NB_SCAN int
    int*   bloff       = blocksum + NB_SCAN;          // NB_SCAN int

    float* out = (float*)d_out;

    k_init<<<512, 256, 0, stream>>>(cnt, c_ws, W_attn, W_feat);
    k_fc<<<(N_NODES * 4 + 255) / 256, 256, 0, stream>>>(h, W_fc, W_attn, z, a_src, a_dst);
    k_hist<<<1024, 256, 0, stream>>>(dst, cnt);
    k_scan_a<<<NB_SCAN, 256, 0, stream>>>(cnt, blocksum);
    k_scan_b<<<1, 256, 0, stream>>>(blocksum, bloff);
    k_scan_c<<<NB_SCAN, 256, 0, stream>>>(cnt, bloff, start, cursor);
    k_scatter<<<(N_EDGES + 255) / 256, 256, 0, stream>>>(src, dst, embed, a_src, a_dst, c_ws,
                                                         cursor, sorted_pair);
    k_gather<<<(N_NODES + 3) / 4, 256, 0, stream>>>(start, cnt, sorted_pair, z, out);
}

// Round 6
// 150.816 us; speedup vs baseline: 2.4400x; 1.2885x over previous
//
#include <hip/hip_runtime.h>

#define N_NODES 50000
#define N_EDGES 800000
#define IN_DIM 128
#define OUT_DIM 64
#define NEG_SLOPE 0.01f

#define SCAN_CHUNK 256
#define NB_SCAN ((N_NODES + SCAN_CHUNK - 1) / SCAN_CHUNK)  // 196

// K0: zero histogram; compute c = W_feat . Wa_feat
__global__ void k_init(int* __restrict__ cnt, float* __restrict__ c_ws,
                       const float* __restrict__ W_attn,
                       const float* __restrict__ W_feat) {
    int i = blockIdx.x * blockDim.x + threadIdx.x;
    int stride = gridDim.x * blockDim.x;
    for (int j = i; j < N_NODES; j += stride) cnt[j] = 0;
    if (blockIdx.x == 0 && threadIdx.x < 64) {
        int lane = threadIdx.x;
        float p = W_feat[lane] * W_attn[128 + lane];
        #pragma unroll
        for (int off = 32; off; off >>= 1) p += __shfl_xor(p, off, 64);
        if (lane == 0) c_ws[0] = p;
    }
}

// K1: z = h @ W_fc, a_src = z . Wa_src, a_dst = z . Wa_dst
// Thread-per-(node, output-quarter): 16 f32 accumulators in registers.
__launch_bounds__(256)
__global__ void k_fc(const float* __restrict__ h,
                     const float* __restrict__ W_fc,
                     const float* __restrict__ W_attn,
                     float* __restrict__ z, float* __restrict__ a_src, float* __restrict__ a_dst) {
    __shared__ float Wlds[IN_DIM * OUT_DIM];  // 32 KB
    const float4* Wg = (const float4*)W_fc;
    float4* Wl = (float4*)Wlds;
    #pragma unroll
    for (int i = 0; i < 8; ++i) Wl[threadIdx.x + i * 256] = Wg[threadIdx.x + i * 256];
    __syncthreads();

    int g = blockIdx.x * 256 + threadIdx.x;
    int n = g >> 2;   // node
    int q = g & 3;    // output quarter: dims [q*16, q*16+16)
    if (n >= N_NODES) return;

    float acc[16];
    #pragma unroll
    for (int i = 0; i < 16; ++i) acc[i] = 0.f;

    const float4* hrow = (const float4*)(h + (size_t)n * IN_DIM);

    for (int kc = 0; kc < IN_DIM / 4; ++kc) {   // 32 iters
        float4 hv = hrow[kc];
        #pragma unroll
        for (int j = 0; j < 4; ++j) {
            float hk = (j == 0) ? hv.x : (j == 1) ? hv.y : (j == 2) ? hv.z : hv.w;
            const float4* Wr = (const float4*)Wlds + (kc * 4 + j) * (OUT_DIM / 4) + q * 4;
            #pragma unroll
            for (int i = 0; i < 4; ++i) {
                float4 wv = Wr[i];
                acc[i * 4 + 0] += hk * wv.x;
                acc[i * 4 + 1] += hk * wv.y;
                acc[i * 4 + 2] += hk * wv.z;
                acc[i * 4 + 3] += hk * wv.w;
            }
        }
    }

    float4* zrow = (float4*)(z + (size_t)n * OUT_DIM) + q * 4;
    #pragma unroll
    for (int i = 0; i < 4; ++i)
        zrow[i] = make_float4(acc[i * 4], acc[i * 4 + 1], acc[i * 4 + 2], acc[i * 4 + 3]);

    const float* wa_s = W_attn + q * 16;
    const float* wa_d = W_attn + OUT_DIM + q * 16;
    float ps = 0.f, pd = 0.f;
    #pragma unroll
    for (int i = 0; i < 16; ++i) { ps += acc[i] * wa_s[i]; pd += acc[i] * wa_d[i]; }
    ps += __shfl_xor(ps, 1, 64); ps += __shfl_xor(ps, 2, 64);
    pd += __shfl_xor(pd, 1, 64); pd += __shfl_xor(pd, 2, 64);
    if (q == 0) { a_src[n] = ps; a_dst[n] = pd; }
}

// K2: histogram of dst
__global__ void k_hist(const int* __restrict__ dst, int* __restrict__ cnt) {
    int i = blockIdx.x * blockDim.x + threadIdx.x;
    int stride = gridDim.x * blockDim.x;
    for (int e = i; e < N_EDGES; e += stride) atomicAdd(&cnt[dst[e]], 1);
}

// K3a: per-block chunk sums
__launch_bounds__(256)
__global__ void k_scan_a(const int* __restrict__ cnt, int* __restrict__ blocksum) {
    __shared__ int red[4];
    int t = threadIdx.x, i = blockIdx.x * SCAN_CHUNK + t;
    int v = (i < N_NODES) ? cnt[i] : 0;
    int s = v;
    #pragma unroll
    for (int off = 32; off; off >>= 1) s += __shfl_xor(s, off, 64);
    if ((t & 63) == 0) red[t >> 6] = s;
    __syncthreads();
    if (t == 0) blocksum[blockIdx.x] = red[0] + red[1] + red[2] + red[3];
}

// K3b: single small block scans blocksum -> exclusive block offsets
__launch_bounds__(256)
__global__ void k_scan_b(const int* __restrict__ blocksum, int* __restrict__ bloff) {
    __shared__ int part[256];
    int t = threadIdx.x;
    int v = (t < NB_SCAN) ? blocksum[t] : 0;
    part[t] = v;
    __syncthreads();
    #pragma unroll
    for (int off = 1; off < 256; off <<= 1) {
        int u = (t >= off) ? part[t - off] : 0;
        __syncthreads();
        part[t] += u;
        __syncthreads();
    }
    if (t < NB_SCAN) bloff[t] = part[t] - v;  // exclusive
}

// K3c: per-block exclusive scan + block offset -> start, cursor
__launch_bounds__(256)
__global__ void k_scan_c(const int* __restrict__ cnt, const int* __restrict__ bloff,
                         int* __restrict__ start, int* __restrict__ cursor) {
    __shared__ int part[256];
    int t = threadIdx.x, i = blockIdx.x * SCAN_CHUNK + t;
    int v = (i < N_NODES) ? cnt[i] : 0;
    part[t] = v;
    __syncthreads();
    #pragma unroll
    for (int off = 1; off < 256; off <<= 1) {
        int u = (t >= off) ? part[t - off] : 0;
        __syncthreads();
        part[t] += u;
        __syncthreads();
    }
    if (i < N_NODES) {
        int r = bloff[blockIdx.x] + part[t] - v;
        start[i] = r;
        cursor[i] = r;
    }
}

// K4: compute ex per edge, scatter packed (src, ex) into dst-sorted buckets
__launch_bounds__(256)
__global__ void k_scatter(const int* __restrict__ src, const int* __restrict__ dst,
                          const float* __restrict__ embed,
                          const float* __restrict__ a_src, const float* __restrict__ a_dst,
                          const float* __restrict__ c_ws,
                          int* __restrict__ cursor,
                          int2* __restrict__ sorted_pair) {
    int e = blockIdx.x * 256 + threadIdx.x;
    if (e >= N_EDGES) return;
    int s = src[e], d = dst[e];
    float ev = a_src[s] + a_dst[d] + c_ws[0] * embed[e];
    ev = (ev >= 0.f) ? ev : NEG_SLOPE * ev;
    float ex = __expf(ev);  // segment-max skipped: softmax shift-invariant, e is O(5)
    int pos = atomicAdd(&cursor[d], 1);
    sorted_pair[pos] = make_int2(s, __float_as_int(ex));
}

// K5: one wave per node: out[n] = sum(ex * z[s]) / sum(ex)
// Lane-parallel pair load (coalesced) + shfl distribute; edge loop unrolled x8
// with register arrays so 8 z-row loads are in flight (MLP to hide LLC latency).
__launch_bounds__(256)
__global__ void k_gather(const int* __restrict__ start, const int* __restrict__ cnt,
                         const int2* __restrict__ sorted_pair,
                         const float* __restrict__ z, float* __restrict__ out) {
    int n = blockIdx.x * 4 + (threadIdx.x >> 6);
    if (n >= N_NODES) return;
    int lane = threadIdx.x & 63;
    int b = start[n], c = cnt[n];
    float acc = 0.f, den = 0.f;

    for (int base = 0; base < c; base += 64) {
        int m = c - base; if (m > 64) m = 64;
        int2 myp = (base + lane < c) ? sorted_pair[b + base + lane] : make_int2(0, 0);
        int j = 0;
        for (; j + 8 <= m; j += 8) {
            int   ss[8];
            float exs[8];
            #pragma unroll
            for (int u = 0; u < 8; ++u) {
                ss[u]  = __shfl(myp.x, j + u, 64);
                exs[u] = __int_as_float(__shfl(myp.y, j + u, 64));
            }
            float zv[8];
            #pragma unroll
            for (int u = 0; u < 8; ++u) zv[u] = z[(size_t)ss[u] * OUT_DIM + lane];
            #pragma unroll
            for (int u = 0; u < 8; ++u) { den += exs[u]; acc += exs[u] * zv[u]; }
        }
        for (; j < m; ++j) {
            int s = __shfl(myp.x, j, 64);
            float ex = __int_as_float(__shfl(myp.y, j, 64));
            den += ex;
            acc += ex * z[(size_t)s * OUT_DIM + lane];
        }
    }
    out[n * OUT_DIM + lane] = c ? acc / den : 0.f;
}

extern "C" void kernel_launch(void* const* d_in, const int* in_sizes, int n_in,
                              void* d_out, int out_size, void* d_ws, size_t ws_size,
                              hipStream_t stream) {
    const float* h      = (const float*)d_in[0];
    const float* embed  = (const float*)d_in[1];
    const int*   src    = (const int*)d_in[2];
    const int*   dst    = (const int*)d_in[3];
    const float* W_fc   = (const float*)d_in[4];
    const float* W_attn = (const float*)d_in[5];
    const float* W_feat = (const float*)d_in[6];

    float* ws          = (float*)d_ws;
    float* z           = ws;                          // N*64 f32
    float* a_src       = z + N_NODES * OUT_DIM;       // N f32
    float* a_dst       = a_src + N_NODES;             // N f32
    float* c_ws        = a_dst + N_NODES;             // 1 f32
    int2*  sorted_pair = (int2*)(c_ws + 1);           // E int2 (8B-aligned: offset is even)
    int*   cnt         = (int*)(sorted_pair + N_EDGES); // N int
    int*   start       = cnt + N_NODES;               // N int
    int*   cursor      = start + N_NODES;             // N int
    int*   blocksum    = cursor + N_NODES;            // NB_SCAN int
    int*   bloff       = blocksum + NB_SCAN;          // NB_SCAN int

    float* out = (float*)d_out;

    k_init<<<512, 256, 0, stream>>>(cnt, c_ws, W_attn, W_feat);
    k_fc<<<(N_NODES * 4 + 255) / 256, 256, 0, stream>>>(h, W_fc, W_attn, z, a_src, a_dst);
    k_hist<<<1024, 256, 0, stream>>>(dst, cnt);
    k_scan_a<<<NB_SCAN, 256, 0, stream>>>(cnt, blocksum);
    k_scan_b<<<1, 256, 0, stream>>>(blocksum, bloff);
    k_scan_c<<<NB_SCAN, 256, 0, stream>>>(cnt, bloff, start, cursor);
    k_scatter<<<(N_EDGES + 255) / 256, 256, 0, stream>>>(src, dst, embed, a_src, a_dst, c_ws,
                                                         cursor, sorted_pair);
    k_gather<<<(N_NODES + 3) / 4, 256, 0, stream>>>(start, cnt, sorted_pair, z, out);
}